// Round 1
// baseline (19.409 us; speedup 1.0000x reference)
//
#include <hip/hip_runtime.h>
#include <cfloat>

#define NN 1024
#define HH 128
#define BB 128
#define AA 243
#define MAXV 9

__global__ __launch_bounds__(256) void apm_fused(
    const float* __restrict__ nf,        // (N,H)
    const float* __restrict__ maskp,     // (B,A)
    const float* __restrict__ W_fcv1,    // (H,64)
    const float* __restrict__ b_fcv1,    // (64)
    const float* __restrict__ W_fcv2,    // (64,1)
    const float* __restrict__ b_fcv2,    // (1)
    const float* __restrict__ W_a2,      // (2H,H)
    const float* __restrict__ b_a2,      // (H)
    const float* __restrict__ W_final,   // (H,3)
    const float* __restrict__ b_final,   // (3)
    const int*   __restrict__ indexmask, // (B,A)
    const int*   __restrict__ bnn,       // (B)
    float* __restrict__ probs_out,       // (B,A)
    float* __restrict__ readout_out)     // (B,1)
{
    const int b = blockIdx.x;
    const int t = threadIdx.x;

    __shared__ float r_lds[MAXV][HH];      // relu(node feats) for this graph
    __shared__ float ai[MAXV][HH + 1];     // +1 pad: bank-conflict-free row reads
    __shared__ float bj[MAXV][HH + 1];
    __shared__ float rd[HH];               // segment sum (raw feats)
    __shared__ float ba[HH];               // b_a2
    __shared__ float wf[HH][3];            // W_final
    __shared__ float sc[AA];               // flat local scores (zero-padded)
    __shared__ float red[256];
    __shared__ int   ired[256];

    // ---- offset = sum_{g<b} batch_num_nodes[g] ----
    int myval = (t < BB) ? bnn[t] : 0;
    ired[t] = (t < b) ? myval : 0;
    __syncthreads();
    #pragma unroll
    for (int stp = 128; stp > 0; stp >>= 1) {
        if (t < stp) ired[t] += ired[t + stp];
        __syncthreads();
    }
    const int off = ired[0];
    const int v   = bnn[b];

    // ---- stage inputs / zero score buffer / segment sum ----
    if (t < AA) sc[t] = 0.f;
    if (t < HH) ba[t] = b_a2[t];
    for (int idx = t; idx < HH * 3; idx += 256) wf[idx / 3][idx % 3] = W_final[idx];
    for (int idx = t; idx < MAXV * HH; idx += 256) {
        int i = idx >> 7, h = idx & (HH - 1);
        float x = (i < v) ? nf[(off + i) * HH + h] : 0.f;
        r_lds[i][h] = fmaxf(x, 0.f);
    }
    if (t < HH) {
        float s = 0.f;
        for (int i = 0; i < v; ++i) s += nf[(off + i) * HH + t];
        rd[t] = s;
    }
    __syncthreads();

    // ---- Ai = r@W_a2[:H], Bj = r@W_a2[H:]  (threads 0-127: Ai col c; 128-255: Bj) ----
    {
        const int c = t & (HH - 1);
        const float* wbase = W_a2 + (t >= 128 ? HH * HH : 0) + c;
        float acc[MAXV];
        #pragma unroll
        for (int i = 0; i < MAXV; ++i) acc[i] = 0.f;
        #pragma unroll 8
        for (int h = 0; h < HH; ++h) {
            float w = wbase[h * HH];           // coalesced across lanes
            #pragma unroll
            for (int i = 0; i < MAXV; ++i) acc[i] += r_lds[i][h] * w;  // LDS broadcast
        }
        float* dst = (t >= 128) ? &bj[0][0] : &ai[0][0];
        #pragma unroll
        for (int i = 0; i < MAXV; ++i) dst[i * (HH + 1) + c] = acc[i];
    }
    __syncthreads();

    // ---- scores for the v*v in-graph pairs; wave 2 does the readout MLP ----
    const int vv = v * v;
    if (t < vv) {
        const int i = t / v, j = t - i * v;
        const float* arow = &ai[i][0];
        const float* brow = &bj[j][0];
        float a0 = b_final[0], a1 = b_final[1], a2 = b_final[2];
        #pragma unroll 4
        for (int h = 0; h < HH; ++h) {
            float hid = fmaxf(arow[h] + brow[h] + ba[h], 0.f);
            a0 += hid * wf[h][0];
            a1 += hid * wf[h][1];
            a2 += hid * wf[h][2];
        }
        // len_matrix == 1 for in-graph pairs; s = (i*v + j)*3 + k
        sc[t * 3 + 0] = a0;
        sc[t * 3 + 1] = a1;
        sc[t * 3 + 2] = a2;
    } else if (t >= 128 && t < 192) {
        // readout: relu(rd @ W_fcv1 + b_fcv1) @ W_fcv2 + b_fcv2  (wave 2, lanes 0-63)
        const int j = t - 128;
        float acc = b_fcv1[j];
        #pragma unroll 4
        for (int h = 0; h < HH; ++h) acc += rd[h] * W_fcv1[h * 64 + j];
        float x = fmaxf(acc, 0.f) * W_fcv2[j];
        #pragma unroll
        for (int o = 32; o > 0; o >>= 1) x += __shfl_down(x, o, 64);
        if (j == 0) readout_out[b] = x + b_fcv2[0];
    }
    __syncthreads();

    // ---- gather via indexmask, add mask, softmax over A=243 ----
    float x = -FLT_MAX;
    if (t < AA) {
        int im = indexmask[b * AA + t];
        x = sc[im] + maskp[b * AA + t];
    }
    red[t] = x;
    __syncthreads();
    #pragma unroll
    for (int stp = 128; stp > 0; stp >>= 1) {
        if (t < stp) red[t] = fmaxf(red[t], red[t + stp]);
        __syncthreads();
    }
    const float mx = red[0];
    __syncthreads();
    float e = (t < AA) ? expf(x - mx) : 0.f;
    red[t] = e;
    __syncthreads();
    #pragma unroll
    for (int stp = 128; stp > 0; stp >>= 1) {
        if (t < stp) red[t] += red[t + stp];
        __syncthreads();
    }
    const float denom = red[0];
    if (t < AA) probs_out[b * AA + t] = e / denom;
}

extern "C" void kernel_launch(void* const* d_in, const int* in_sizes, int n_in,
                              void* d_out, int out_size, void* d_ws, size_t ws_size,
                              hipStream_t stream) {
    const float* nf      = (const float*)d_in[0];
    // d_in[1] = len_vec: block-diagonal indicator, == 1 for all in-graph pairs -> unused
    const float* maskp   = (const float*)d_in[2];
    const float* W_fcv1  = (const float*)d_in[3];
    const float* b_fcv1  = (const float*)d_in[4];
    const float* W_fcv2  = (const float*)d_in[5];
    const float* b_fcv2  = (const float*)d_in[6];
    const float* W_a2    = (const float*)d_in[7];
    const float* b_a2    = (const float*)d_in[8];
    const float* W_final = (const float*)d_in[9];
    const float* b_final = (const float*)d_in[10];
    const int*   indexmask = (const int*)d_in[11];
    // d_in[12] = segment_ids: contiguous blocks; offsets derived from batch_num_nodes
    const int*   bnn       = (const int*)d_in[13];

    float* probs   = (float*)d_out;          // (B, A) first in return order
    float* readout = probs + BB * AA;        // (B, 1) second

    apm_fused<<<BB, 256, 0, stream>>>(nf, maskp, W_fcv1, b_fcv1, W_fcv2, b_fcv2,
                                      W_a2, b_a2, W_final, b_final,
                                      indexmask, bnn, probs, readout);
}

// Round 2
// 18.299 us; speedup vs baseline: 1.0606x; 1.0606x over previous
//
#include <hip/hip_runtime.h>
#include <cfloat>

#define HH 128
#define BB 128
#define AA 243
#define MAXV 9

__device__ __forceinline__ float rl(float x, int l) {
    return __builtin_bit_cast(float, __builtin_amdgcn_readlane(__builtin_bit_cast(int, x), l));
}

__global__ __launch_bounds__(256) void apm_fused(
    const float* __restrict__ nf,        // (N,H)
    const float* __restrict__ maskp,     // (B,A)
    const float* __restrict__ W_fcv1,    // (H,64)
    const float* __restrict__ b_fcv1,    // (64)
    const float* __restrict__ W_fcv2,    // (64,1)
    const float* __restrict__ b_fcv2,    // (1)
    const float* __restrict__ W_a2,      // (2H,H)
    const float* __restrict__ b_a2,      // (H)
    const float* __restrict__ W_final,   // (H,3)
    const float* __restrict__ b_final,   // (3)
    const int*   __restrict__ indexmask, // (B,A)
    const int*   __restrict__ bnn,       // (B)
    float* __restrict__ probs_out,       // (B,A)
    float* __restrict__ readout_out)     // (B,1)
{
    const int b    = blockIdx.x;
    const int t    = threadIdx.x;
    const int lane = t & 63;
    const int w    = t >> 6;

    __shared__ float abia[MAXV][132];   // Ai + b_a2 folded; 132 stride: 16B-aligned rows
    __shared__ float bjs[MAXV][132];    // Bj
    __shared__ float wfT[3][HH];        // W_final transposed
    __shared__ float sc[AA + 1];        // local flat scores (zero-padded tail)
    __shared__ float xred[8];

    // ---- early independent loads (hide latency under everything below) ----
    float mk = 0.f, bfin = 0.f; int im = 0;
    if (t < AA) {
        im   = indexmask[b * AA + t];
        mk   = maskp[b * AA + t];
        bfin = b_final[t % 3];          // t = 3*pair + k  ->  k = t%3
    }
    for (int idx = t; idx < 3 * HH; idx += 256) {
        int h = idx / 3, k = idx - 3 * h;
        wfT[k][h] = W_final[idx];
    }

    // ---- graph offset: per-wave shuffle reduce (no barrier needed) ----
    int ov = 0;
    if (lane < b)      ov += bnn[lane];
    if (lane + 64 < b) ov += bnn[lane + 64];
    #pragma unroll
    for (int o = 1; o < 64; o <<= 1) ov += __shfl_xor(ov, o, 64);
    const int off = ov;
    const int v   = bnn[b];

    // ---- node rows -> per-wave registers (lane l holds h=l and h=64+l) ----
    float rlo[MAXV], rhi[MAXV];
    float rdlo = 0.f, rdhi = 0.f;       // raw (pre-relu) sums for readout
    #pragma unroll
    for (int i = 0; i < MAXV; ++i) {
        float xlo = 0.f, xhi = 0.f;
        if (i < v) {
            xlo = nf[(off + i) * HH + lane];
            xhi = nf[(off + i) * HH + 64 + lane];
        }
        rdlo += xlo; rdhi += xhi;
        rlo[i] = fmaxf(xlo, 0.f);
        rhi[i] = fmaxf(xhi, 0.f);
    }

    // ---- GEMV: waves 0,1 -> Ai cols [0,64),[64,128); waves 2,3 -> Bj.
    //      Broadcast of r via compile-time v_readlane: zero LDS traffic. ----
    const int c = ((w & 1) << 6) | lane;
    const float* Wb = W_a2 + ((w >> 1) ? HH * HH : 0) + c;
    float acc[MAXV];
    #pragma unroll
    for (int i = 0; i < MAXV; ++i) acc[i] = 0.f;
    #pragma unroll
    for (int h = 0; h < 64; ++h) {
        float wv = Wb[h * HH];
        #pragma unroll
        for (int i = 0; i < MAXV; ++i) acc[i] = fmaf(rl(rlo[i], h), wv, acc[i]);
    }
    #pragma unroll
    for (int h = 0; h < 64; ++h) {
        float wv = Wb[(64 + h) * HH];
        #pragma unroll
        for (int i = 0; i < MAXV; ++i) acc[i] = fmaf(rl(rhi[i], h), wv, acc[i]);
    }

    if (w < 2) {
        float bav = b_a2[c];
        #pragma unroll
        for (int i = 0; i < MAXV; ++i) abia[i][c] = acc[i] + bav;
    } else {
        #pragma unroll
        for (int i = 0; i < MAXV; ++i) bjs[i][c] = acc[i];
    }
    __syncthreads();                                   // barrier 1

    const int vv3 = v * v * 3;
    if (t < AA && t >= vv3) sc[t] = 0.f;               // zero pad tail

    // ---- readout MLP: wave 3, readlane broadcast of segment-sum ----
    if (w == 3) {
        float a2 = b_fcv1[lane];
        #pragma unroll
        for (int h = 0; h < 64; ++h)
            a2 = fmaf(rl(rdlo, h), W_fcv1[h * 64 + lane], a2);
        #pragma unroll
        for (int h = 0; h < 64; ++h)
            a2 = fmaf(rl(rdhi, h), W_fcv1[(64 + h) * 64 + lane], a2);
        float x = fmaxf(a2, 0.f) * W_fcv2[lane];
        #pragma unroll
        for (int o = 1; o < 64; o <<= 1) x += __shfl_xor(x, o, 64);
        if (lane == 0) readout_out[b] = x + b_fcv2[0];
    }

    // ---- pair scoring: one thread per (pair, k), float4 LDS reads ----
    if (t < vv3) {
        const int pair = t / 3, k = t - 3 * pair;
        const int i = pair / v, j = pair - i * v;
        const float* ar = &abia[i][0];
        const float* br = &bjs[j][0];
        const float* wk = &wfT[k][0];
        float s = bfin;
        #pragma unroll 8
        for (int h = 0; h < HH; h += 4) {
            float4 a4 = *(const float4*)(ar + h);
            float4 b4 = *(const float4*)(br + h);
            float4 w4 = *(const float4*)(wk + h);
            s = fmaf(fmaxf(a4.x + b4.x, 0.f), w4.x, s);
            s = fmaf(fmaxf(a4.y + b4.y, 0.f), w4.y, s);
            s = fmaf(fmaxf(a4.z + b4.z, 0.f), w4.z, s);
            s = fmaf(fmaxf(a4.w + b4.w, 0.f), w4.w, s);
        }
        sc[t] = s;
    }
    __syncthreads();                                   // barrier 2

    // ---- gather + softmax (per-wave shuffle reduce, 4-slot cross-wave) ----
    float x = -FLT_MAX;
    if (t < AA) x = sc[im] + mk;
    float m = x;
    #pragma unroll
    for (int o = 1; o < 64; o <<= 1) m = fmaxf(m, __shfl_xor(m, o, 64));
    if (lane == 0) xred[w] = m;
    __syncthreads();                                   // barrier 3
    m = fmaxf(fmaxf(xred[0], xred[1]), fmaxf(xred[2], xred[3]));
    float e = (t < AA) ? __expf(x - m) : 0.f;
    float s = e;
    #pragma unroll
    for (int o = 1; o < 64; o <<= 1) s += __shfl_xor(s, o, 64);
    if (lane == 0) xred[4 + w] = s;
    __syncthreads();                                   // barrier 4
    const float denom = (xred[4] + xred[5]) + (xred[6] + xred[7]);
    const float rden  = __builtin_amdgcn_rcpf(denom);
    if (t < AA) probs_out[b * AA + t] = e * rden;
}

extern "C" void kernel_launch(void* const* d_in, const int* in_sizes, int n_in,
                              void* d_out, int out_size, void* d_ws, size_t ws_size,
                              hipStream_t stream) {
    const float* nf      = (const float*)d_in[0];
    // d_in[1] = len_vec (block-diagonal indicator; ==1 for in-graph pairs) -> unused
    const float* maskp   = (const float*)d_in[2];
    const float* W_fcv1  = (const float*)d_in[3];
    const float* b_fcv1  = (const float*)d_in[4];
    const float* W_fcv2  = (const float*)d_in[5];
    const float* b_fcv2  = (const float*)d_in[6];
    const float* W_a2    = (const float*)d_in[7];
    const float* b_a2    = (const float*)d_in[8];
    const float* W_final = (const float*)d_in[9];
    const float* b_final = (const float*)d_in[10];
    const int*   indexmask = (const int*)d_in[11];
    // d_in[12] = segment_ids (contiguous blocks; offsets derived from bnn)
    const int*   bnn       = (const int*)d_in[13];

    float* probs   = (float*)d_out;
    float* readout = probs + BB * AA;

    apm_fused<<<BB, 256, 0, stream>>>(nf, maskp, W_fcv1, b_fcv1, W_fcv2, b_fcv2,
                                      W_a2, b_a2, W_final, b_final,
                                      indexmask, bnn, probs, readout);
}

// Round 3
// 15.527 us; speedup vs baseline: 1.2500x; 1.1786x over previous
//
#include <hip/hip_runtime.h>
#include <cfloat>

#define HH 128
#define BB 128
#define AA 243
#define MAXV 9

__device__ __forceinline__ float rl(float x, int l) {
    return __builtin_bit_cast(float, __builtin_amdgcn_readlane(__builtin_bit_cast(int, x), l));
}

__global__ __launch_bounds__(512) void apm_fused(
    const float* __restrict__ nf,        // (N,H)
    const float* __restrict__ maskp,     // (B,A)
    const float* __restrict__ W_fcv1,    // (H,64)
    const float* __restrict__ b_fcv1,    // (64)
    const float* __restrict__ W_fcv2,    // (64,1)
    const float* __restrict__ b_fcv2,    // (1)
    const float* __restrict__ W_a2,      // (2H,H)
    const float* __restrict__ b_a2,      // (H)
    const float* __restrict__ W_final,   // (H,3)
    const float* __restrict__ b_final,   // (3)
    const int*   __restrict__ indexmask, // (B,A)
    const int*   __restrict__ bnn,       // (B)
    float* __restrict__ probs_out,       // (B,A)
    float* __restrict__ readout_out)     // (B,1)
{
    const int b    = blockIdx.x;
    const int t    = threadIdx.x;
    const int lane = t & 63;
    const int w    = t >> 6;
    const int matB = w >> 2;        // 0 -> Ai (W_a2[:H]), 1 -> Bj (W_a2[H:])
    const int hh   = (w >> 1) & 1;  // which 64-wide h-half this wave reduces
    const int ch   = w & 1;         // which 64-wide column-half this wave produces
    const int c    = (ch << 6) | lane;

    __shared__ float pA[2][MAXV][132];  // [h-half][i][c]; pA[0] becomes Ai + b_a2
    __shared__ float pB[2][MAXV][132];
    __shared__ float wfT[3][HH];        // W_final transposed
    __shared__ float sc[AA + 1];        // local flat scores
    __shared__ float rdbuf[HH];         // segment-sum (pre-relu)
    __shared__ float rout[64];          // readout hi-half partial
    __shared__ float xred[16];

    // ---- W_a2 slice -> 64 registers, issued FIRST (independent loads that
    //      hide under the offset/nf dependency chain). Grid-limited occupancy
    //      (128 blocks / 256 CUs) makes the VGPR cost free. ----
    const float* Wb = W_a2 + matB * (HH * HH) + (hh * 64) * HH + c;
    float wreg[64];
    #pragma unroll
    for (int h = 0; h < 64; ++h) wreg[h] = Wb[h * HH];

    // ---- early independent loads for the softmax phase ----
    float mk = 0.f, bfin = 0.f; int im = 0;
    if (t < AA) {
        im   = indexmask[b * AA + t];
        mk   = maskp[b * AA + t];
        bfin = b_final[t % 3];          // t = 3*pair + k
    }
    for (int idx = t; idx < 3 * HH; idx += 512) {
        int h = idx / 3, k = idx - 3 * h;
        wfT[k][h] = W_final[idx];
    }

    // ---- graph offset: per-wave shuffle reduce (no barrier) ----
    int ov = 0;
    if (lane < b)      ov += bnn[lane];
    if (lane + 64 < b) ov += bnn[lane + 64];
    #pragma unroll
    for (int o = 1; o < 64; o <<= 1) ov += __shfl_xor(ov, o, 64);
    const int off = ov;
    const int v   = bnn[b];

    // ---- node-row slice (this wave's h-half) -> registers ----
    float rr[MAXV]; float rdsum = 0.f;
    #pragma unroll
    for (int i = 0; i < MAXV; ++i) {
        float x = (i < v) ? nf[(off + i) * HH + hh * 64 + lane] : 0.f;
        rdsum += x;                      // raw (pre-relu) for readout
        rr[i]  = fmaxf(x, 0.f);
    }
    if (w == 0) rdbuf[lane]      = rdsum;
    if (w == 2) rdbuf[64 + lane] = rdsum;

    // ---- GEMV partial: 64 h-iters, readlane broadcast (pure VALU) ----
    float acc[MAXV];
    #pragma unroll
    for (int i = 0; i < MAXV; ++i) acc[i] = 0.f;
    #pragma unroll
    for (int h = 0; h < 64; ++h) {
        float wv = wreg[h];
        #pragma unroll
        for (int i = 0; i < MAXV; ++i) acc[i] = fmaf(rl(rr[i], h), wv, acc[i]);
    }
    {
        float (*dst)[132] = matB ? pB[hh] : pA[hh];
        #pragma unroll
        for (int i = 0; i < MAXV; ++i) dst[i][c] = acc[i];
    }
    __syncthreads();                                   // barrier 1

    const int vv3 = v * v * 3;
    if (t < AA && t >= vv3) sc[t] = 0.f;

    float a2lo = 0.f;                    // wave-7 readout partial (reg across barrier)
    if (w < 6) {
        // ---- combine h-half partials, fold b_a2 (waves 0-5) ----
        #pragma unroll
        for (int rep = 0; rep < 3; ++rep) {
            int idx = t + rep * 384;
            int i = idx >> 7, cc = idx & 127;
            pA[0][i][cc] = pA[0][i][cc] + pA[1][i][cc] + b_a2[cc];
            pB[0][i][cc] += pB[1][i][cc];
        }
    } else if (w == 6) {
        // ---- readout hi-half partial ----
        float rd1 = rdbuf[64 + lane];
        float a2 = 0.f;
        #pragma unroll
        for (int h = 0; h < 64; ++h)
            a2 = fmaf(rl(rd1, h), W_fcv1[(64 + h) * 64 + lane], a2);
        rout[lane] = a2;
    } else {
        // ---- readout lo-half partial (stays in register) ----
        float rd0 = rdbuf[lane];
        a2lo = b_fcv1[lane];
        #pragma unroll
        for (int h = 0; h < 64; ++h)
            a2lo = fmaf(rl(rd0, h), W_fcv1[h * 64 + lane], a2lo);
    }
    __syncthreads();                                   // barrier 2

    // ---- pair scoring (waves 0-3) ∥ readout finish (wave 7) ----
    if (t < vv3) {
        const int pair = t / 3, k = t - 3 * pair;
        const int i = pair / v, j = pair - i * v;
        const float* ar = &pA[0][i][0];
        const float* br = &pB[0][j][0];
        const float* wk = &wfT[k][0];
        float s = bfin;
        #pragma unroll 8
        for (int h = 0; h < HH; h += 4) {
            float4 a4 = *(const float4*)(ar + h);
            float4 b4 = *(const float4*)(br + h);
            float4 w4 = *(const float4*)(wk + h);
            s = fmaf(fmaxf(a4.x + b4.x, 0.f), w4.x, s);
            s = fmaf(fmaxf(a4.y + b4.y, 0.f), w4.y, s);
            s = fmaf(fmaxf(a4.z + b4.z, 0.f), w4.z, s);
            s = fmaf(fmaxf(a4.w + b4.w, 0.f), w4.w, s);
        }
        sc[t] = s;
    } else if (w == 7) {
        float a2 = a2lo + rout[lane];
        float x = fmaxf(a2, 0.f) * W_fcv2[lane];
        #pragma unroll
        for (int o = 1; o < 64; o <<= 1) x += __shfl_xor(x, o, 64);
        if (lane == 0) readout_out[b] = x + b_fcv2[0];
    }
    __syncthreads();                                   // barrier 3

    // ---- gather + softmax ----
    float x = -FLT_MAX;
    if (t < AA) x = sc[im] + mk;
    float m = x;
    #pragma unroll
    for (int o = 1; o < 64; o <<= 1) m = fmaxf(m, __shfl_xor(m, o, 64));
    if (lane == 0) xred[w] = m;
    __syncthreads();                                   // barrier 4
    m = fmaxf(fmaxf(xred[0], xred[1]), fmaxf(xred[2], xred[3]));
    float e = (t < AA) ? __expf(x - m) : 0.f;
    float s = e;
    #pragma unroll
    for (int o = 1; o < 64; o <<= 1) s += __shfl_xor(s, o, 64);
    if (lane == 0) xred[8 + w] = s;
    __syncthreads();                                   // barrier 5
    const float denom = (xred[8] + xred[9]) + (xred[10] + xred[11]);
    const float rden  = __builtin_amdgcn_rcpf(denom);
    if (t < AA) probs_out[b * AA + t] = e * rden;
}

extern "C" void kernel_launch(void* const* d_in, const int* in_sizes, int n_in,
                              void* d_out, int out_size, void* d_ws, size_t ws_size,
                              hipStream_t stream) {
    const float* nf      = (const float*)d_in[0];
    // d_in[1] = len_vec (==1 for in-graph pairs) -> unused
    const float* maskp   = (const float*)d_in[2];
    const float* W_fcv1  = (const float*)d_in[3];
    const float* b_fcv1  = (const float*)d_in[4];
    const float* W_fcv2  = (const float*)d_in[5];
    const float* b_fcv2  = (const float*)d_in[6];
    const float* W_a2    = (const float*)d_in[7];
    const float* b_a2    = (const float*)d_in[8];
    const float* W_final = (const float*)d_in[9];
    const float* b_final = (const float*)d_in[10];
    const int*   indexmask = (const int*)d_in[11];
    // d_in[12] = segment_ids (contiguous blocks) -> offsets derived from bnn
    const int*   bnn       = (const int*)d_in[13];

    float* probs   = (float*)d_out;
    float* readout = probs + BB * AA;

    apm_fused<<<BB, 512, 0, stream>>>(nf, maskp, W_fcv1, b_fcv1, W_fcv2, b_fcv2,
                                      W_a2, b_a2, W_final, b_final,
                                      indexmask, bnn, probs, readout);
}

// Round 4
// 13.905 us; speedup vs baseline: 1.3959x; 1.1167x over previous
//
#include <hip/hip_runtime.h>
#include <cfloat>

#define HH 128
#define BB 128
#define AA 243
#define MAXV 9

__device__ __forceinline__ float rl(float x, int l) {
    return __builtin_bit_cast(float, __builtin_amdgcn_readlane(__builtin_bit_cast(int, x), l));
}

__global__ __launch_bounds__(512) void apm_fused(
    const float* __restrict__ nf,        // (N,H)
    const float* __restrict__ maskp,     // (B,A)
    const float* __restrict__ W_fcv1,    // (H,64)
    const float* __restrict__ b_fcv1,    // (64)
    const float* __restrict__ W_fcv2,    // (64,1)
    const float* __restrict__ b_fcv2,    // (1)
    const float* __restrict__ W_a2,      // (2H,H)
    const float* __restrict__ b_a2,      // (H)
    const float* __restrict__ W_final,   // (H,3)
    const float* __restrict__ b_final,   // (3)
    const int*   __restrict__ indexmask, // (B,A)
    const int*   __restrict__ bnn,       // (B)
    float* __restrict__ probs_out,       // (B,A)
    float* __restrict__ readout_out)     // (B,1)
{
    const int b    = blockIdx.x;
    const int t    = threadIdx.x;
    const int lane = t & 63;
    const int w    = t >> 6;
    const int matB = w >> 2;        // 0 -> Ai (W_a2[:H]), 1 -> Bj (W_a2[H:])
    const int hq   = w & 3;         // 32-wide h-quarter this wave reduces
    const int c0   = lane << 1;     // two adjacent columns per thread (pk-fma)

    __shared__ float pS[2][4][MAXV][132];  // [mat][h-quarter][i][col]; [.][0] becomes final
    __shared__ float wfT[3][HH];           // W_final transposed
    __shared__ float sc[AA + 1];           // local flat scores
    __shared__ float rdbuf[HH];            // segment-sum (pre-relu)
    __shared__ float rout[64];             // readout hi-half partial
    __shared__ float xred[16];

    // ---- bnn first: it heads the longest dependency chain (off -> nf -> GEMV) ----
    int ov = 0;
    if (lane < b)      ov += bnn[lane];
    if (lane + 64 < b) ov += bnn[lane + 64];
    const int v = bnn[b];                  // uniform -> scalar load

    // ---- W_a2 slice -> 32 float2 registers (independent; hides under bnn/nf chain) ----
    const float* Wb = W_a2 + matB * (HH * HH) + (hq * 32) * HH + c0;
    float2 wreg[32];
    #pragma unroll
    for (int h = 0; h < 32; ++h) wreg[h] = *(const float2*)(Wb + h * HH);

    // ---- early independent loads for the softmax phase ----
    float mk = 0.f, bfin = 0.f; int im = 0;
    if (t < AA) {
        im   = indexmask[b * AA + t];
        mk   = maskp[b * AA + t];
        bfin = b_final[t % 3];             // t = 3*pair + k
    }
    if (t < 3 * HH) {
        int h = t / 3, k = t - 3 * h;
        wfT[k][h] = W_final[t];
    }

    // ---- graph offset: per-wave shuffle reduce ----
    #pragma unroll
    for (int o = 1; o < 64; o <<= 1) ov += __shfl_xor(ov, o, 64);
    const int off = ov;

    // ---- node-row slice (this wave's 32-wide h-quarter; lanes 32-63 duplicate) ----
    const int hbase = hq * 32 + (lane & 31);
    float rr[MAXV]; float rdsum = 0.f;
    #pragma unroll
    for (int i = 0; i < MAXV; ++i) {
        float x = (i < v) ? nf[(off + i) * HH + hbase] : 0.f;
        rdsum += x;                        // raw (pre-relu) for readout
        rr[i]  = fmaxf(x, 0.f);
    }
    if (w < 4 && lane < 32) rdbuf[hbase] = rdsum;

    // ---- GEMV quarter: 32 h-iters, readlane broadcast, 2 cols/thread ----
    float accx[MAXV], accy[MAXV];
    #pragma unroll
    for (int i = 0; i < MAXV; ++i) { accx[i] = 0.f; accy[i] = 0.f; }
    #pragma unroll
    for (int h = 0; h < 32; ++h) {
        const float wx = wreg[h].x, wy = wreg[h].y;
        #pragma unroll
        for (int i = 0; i < MAXV; ++i) {
            const float s = rl(rr[i], h);
            accx[i] = fmaf(s, wx, accx[i]);
            accy[i] = fmaf(s, wy, accy[i]);
        }
    }
    #pragma unroll
    for (int i = 0; i < MAXV; ++i)
        *(float2*)&pS[matB][hq][i][c0] = make_float2(accx[i], accy[i]);
    __syncthreads();                                   // barrier 1

    const int vv3 = v * v * 3;
    if (t < AA && t >= vv3) sc[t] = 0.f;

    float a2lo = 0.f;                      // wave-7 readout partial (reg across barrier)
    if (w < 6) {
        // ---- combine 4 h-quarter partials; fold b_a2 into A (waves 0-5) ----
        #pragma unroll
        for (int rep = 0; rep < 3; ++rep) {
            int idx = t + rep * 384;       // 2 mats x 9 i x 64 float2-cols = 1152
            int m   = idx / 576;
            int rem = idx - m * 576;
            int i   = rem >> 6;
            int cc  = (rem & 63) << 1;
            float2 p0 = *(const float2*)&pS[m][0][i][cc];
            float2 p1 = *(const float2*)&pS[m][1][i][cc];
            float2 p2 = *(const float2*)&pS[m][2][i][cc];
            float2 p3 = *(const float2*)&pS[m][3][i][cc];
            float sx = (p0.x + p1.x) + (p2.x + p3.x);
            float sy = (p0.y + p1.y) + (p2.y + p3.y);
            if (m == 0) { sx += b_a2[cc]; sy += b_a2[cc + 1]; }
            *(float2*)&pS[m][0][i][cc] = make_float2(sx, sy);
        }
    } else if (w == 6) {
        // ---- readout hi-half partial (4 independent acc chains) ----
        float rd1 = rdbuf[64 + lane];
        float q0 = 0.f, q1 = 0.f, q2 = 0.f, q3 = 0.f;
        #pragma unroll
        for (int h = 0; h < 16; ++h) {
            q0 = fmaf(rl(rd1, h),      W_fcv1[(64 + h)  * 64 + lane], q0);
            q1 = fmaf(rl(rd1, h + 16), W_fcv1[(80 + h)  * 64 + lane], q1);
            q2 = fmaf(rl(rd1, h + 32), W_fcv1[(96 + h)  * 64 + lane], q2);
            q3 = fmaf(rl(rd1, h + 48), W_fcv1[(112 + h) * 64 + lane], q3);
        }
        rout[lane] = (q0 + q1) + (q2 + q3);
    } else {
        // ---- readout lo-half partial (stays in register) ----
        float rd0 = rdbuf[lane];
        float q0 = b_fcv1[lane], q1 = 0.f, q2 = 0.f, q3 = 0.f;
        #pragma unroll
        for (int h = 0; h < 16; ++h) {
            q0 = fmaf(rl(rd0, h),      W_fcv1[h        * 64 + lane], q0);
            q1 = fmaf(rl(rd0, h + 16), W_fcv1[(16 + h) * 64 + lane], q1);
            q2 = fmaf(rl(rd0, h + 32), W_fcv1[(32 + h) * 64 + lane], q2);
            q3 = fmaf(rl(rd0, h + 48), W_fcv1[(48 + h) * 64 + lane], q3);
        }
        a2lo = (q0 + q1) + (q2 + q3);
    }
    __syncthreads();                                   // barrier 2

    // ---- pair scoring (4 indep accumulators) ∥ readout finish (wave 7) ----
    if (t < vv3) {
        const int pair = t / 3, k = t - 3 * pair;
        const int i = pair / v, j = pair - i * v;
        const float* ar = &pS[0][0][i][0];
        const float* br = &pS[1][0][j][0];
        const float* wk = &wfT[k][0];
        float s0 = 0.f, s1 = 0.f, s2 = 0.f, s3 = 0.f;
        #pragma unroll 8
        for (int h = 0; h < HH; h += 4) {
            float4 a4 = *(const float4*)(ar + h);
            float4 b4 = *(const float4*)(br + h);
            float4 w4 = *(const float4*)(wk + h);
            s0 = fmaf(fmaxf(a4.x + b4.x, 0.f), w4.x, s0);
            s1 = fmaf(fmaxf(a4.y + b4.y, 0.f), w4.y, s1);
            s2 = fmaf(fmaxf(a4.z + b4.z, 0.f), w4.z, s2);
            s3 = fmaf(fmaxf(a4.w + b4.w, 0.f), w4.w, s3);
        }
        sc[t] = bfin + ((s0 + s1) + (s2 + s3));
    } else if (w == 7) {
        float a2 = a2lo + rout[lane];
        float x = fmaxf(a2, 0.f) * W_fcv2[lane];
        #pragma unroll
        for (int o = 1; o < 64; o <<= 1) x += __shfl_xor(x, o, 64);
        if (lane == 0) readout_out[b] = x + b_fcv2[0];
    }
    __syncthreads();                                   // barrier 3

    // ---- gather + softmax ----
    float x = -FLT_MAX;
    if (t < AA) x = sc[im] + mk;
    float m = x;
    #pragma unroll
    for (int o = 1; o < 64; o <<= 1) m = fmaxf(m, __shfl_xor(m, o, 64));
    if (lane == 0) xred[w] = m;
    __syncthreads();                                   // barrier 4
    m = fmaxf(fmaxf(xred[0], xred[1]), fmaxf(xred[2], xred[3]));
    float e = (t < AA) ? __expf(x - m) : 0.f;
    float s = e;
    #pragma unroll
    for (int o = 1; o < 64; o <<= 1) s += __shfl_xor(s, o, 64);
    if (lane == 0) xred[8 + w] = s;
    __syncthreads();                                   // barrier 5
    const float denom = (xred[8] + xred[9]) + (xred[10] + xred[11]);
    const float rden  = __builtin_amdgcn_rcpf(denom);
    if (t < AA) probs_out[b * AA + t] = e * rden;
}

extern "C" void kernel_launch(void* const* d_in, const int* in_sizes, int n_in,
                              void* d_out, int out_size, void* d_ws, size_t ws_size,
                              hipStream_t stream) {
    const float* nf      = (const float*)d_in[0];
    // d_in[1] = len_vec (==1 for in-graph pairs) -> unused
    const float* maskp   = (const float*)d_in[2];
    const float* W_fcv1  = (const float*)d_in[3];
    const float* b_fcv1  = (const float*)d_in[4];
    const float* W_fcv2  = (const float*)d_in[5];
    const float* b_fcv2  = (const float*)d_in[6];
    const float* W_a2    = (const float*)d_in[7];
    const float* b_a2    = (const float*)d_in[8];
    const float* W_final = (const float*)d_in[9];
    const float* b_final = (const float*)d_in[10];
    const int*   indexmask = (const int*)d_in[11];
    // d_in[12] = segment_ids (contiguous blocks) -> offsets derived from bnn
    const int*   bnn       = (const int*)d_in[13];

    float* probs   = (float*)d_out;
    float* readout = probs + BB * AA;

    apm_fused<<<BB, 512, 0, stream>>>(nf, maskp, W_fcv1, b_fcv1, W_fcv2, b_fcv2,
                                      W_a2, b_a2, W_final, b_final,
                                      indexmask, bnn, probs, readout);
}

// Round 5
// 13.517 us; speedup vs baseline: 1.4359x; 1.0287x over previous
//
#include <hip/hip_runtime.h>
#include <cfloat>

#define HH 128
#define BB 128
#define AA 243
#define MAXV 9

typedef float v2f __attribute__((ext_vector_type(2)));

__device__ __forceinline__ int rli(float x, int l) {
    return __builtin_amdgcn_readlane(__builtin_bit_cast(int, x), l);
}
__device__ __forceinline__ float rl(float x, int l) {
    return __builtin_bit_cast(float, __builtin_amdgcn_readlane(__builtin_bit_cast(int, x), l));
}
__device__ __forceinline__ unsigned long long pack2(int lo, int hi) {
    int2 p; p.x = lo; p.y = hi;
    return __builtin_bit_cast(unsigned long long, p);  // REG_SEQUENCE: no ALU cost
}
// acc = broadcast(sv.lo) * w + acc   (packed 2xf32, scalar from SGPR-pair low reg)
__device__ __forceinline__ void pk_fma_lo(v2f& acc, unsigned long long sv, v2f w) {
    asm("v_pk_fma_f32 %0, %2, %1, %0 op_sel:[0,0,0] op_sel_hi:[0,1,1]"
        : "+v"(acc) : "v"(w), "s"(sv));
}
// acc = broadcast(sv.hi) * w + acc
__device__ __forceinline__ void pk_fma_hi(v2f& acc, unsigned long long sv, v2f w) {
    asm("v_pk_fma_f32 %0, %2, %1, %0 op_sel:[1,0,0] op_sel_hi:[1,1,1]"
        : "+v"(acc) : "v"(w), "s"(sv));
}

// Per-wave GEMV quarter: NV node rows, 32-wide h-slice, 2 adjacent cols/thread.
template<int NV, bool PRED>
__device__ __forceinline__ void gemv_phase(
    const float* __restrict__ nf, int off, int v, int hbase,
    bool write_rd, float* __restrict__ rdbuf,
    const v2f* __restrict__ wreg, float* __restrict__ dst, int c0)
{
    float rr[NV]; float rdsum = 0.f;
    #pragma unroll
    for (int i = 0; i < NV; ++i) {
        float x = PRED ? ((i < v) ? nf[(off + i) * HH + hbase] : 0.f)
                       : nf[(off + i) * HH + hbase];
        rdsum += x;                  // raw (pre-relu) for readout
        rr[i] = fmaxf(x, 0.f);
    }
    if (write_rd) rdbuf[hbase] = rdsum;
    v2f acc[NV];
    #pragma unroll
    for (int i = 0; i < NV; ++i) acc[i] = (v2f)(0.0f);
    #pragma unroll
    for (int h = 0; h < 32; h += 2) {
        const v2f w0 = wreg[h], w1 = wreg[h + 1];
        #pragma unroll
        for (int i = 0; i < NV; ++i) {
            unsigned long long sv = pack2(rli(rr[i], h), rli(rr[i], h + 1));
            pk_fma_lo(acc[i], sv, w0);
            pk_fma_hi(acc[i], sv, w1);
        }
    }
    #pragma unroll
    for (int i = 0; i < NV; ++i) *(v2f*)(dst + i * 132 + c0) = acc[i];
}

__global__ __launch_bounds__(512) void apm_fused(
    const float* __restrict__ nf,        // (N,H)
    const float* __restrict__ maskp,     // (B,A)
    const float* __restrict__ W_fcv1,    // (H,64)
    const float* __restrict__ b_fcv1,    // (64)
    const float* __restrict__ W_fcv2,    // (64,1)
    const float* __restrict__ b_fcv2,    // (1)
    const float* __restrict__ W_a2,      // (2H,H)
    const float* __restrict__ b_a2,      // (H)
    const float* __restrict__ W_final,   // (H,3)
    const float* __restrict__ b_final,   // (3)
    const int*   __restrict__ indexmask, // (B,A)
    const int*   __restrict__ bnn,       // (B)
    float* __restrict__ probs_out,       // (B,A)
    float* __restrict__ readout_out)     // (B,1)
{
    const int b    = blockIdx.x;
    const int t    = threadIdx.x;
    const int lane = t & 63;
    const int w    = t >> 6;
    const int matB = w >> 2;        // 0 -> Ai (W_a2[:H]), 1 -> Bj (W_a2[H:])
    const int hq   = w & 3;         // 32-wide h-quarter this wave reduces
    const int c0   = lane << 1;     // two adjacent columns per thread

    __shared__ float pS[2][4][MAXV][132];  // [mat][h-quarter][i][col]
    __shared__ float wfT[3][HH];           // W_final transposed
    __shared__ float sc[AA + 1];           // local flat scores
    __shared__ float rdbuf[HH];            // segment-sum (pre-relu)
    __shared__ float rout[64];             // readout hi-half partial
    __shared__ float2 xr2[8];              // per-wave (max, sum) for softmax

    // ---- bnn first: heads the longest chain (off -> nf -> GEMV) ----
    int ov = 0;
    if (lane < b)      ov += bnn[lane];
    if (lane + 64 < b) ov += bnn[lane + 64];
    const int v = bnn[b];                  // uniform

    // ---- W_a2 slice -> 32 v2f registers (independent; hides under bnn chain) ----
    const float* Wb = W_a2 + matB * (HH * HH) + (hq * 32) * HH + c0;
    v2f wreg[32];
    #pragma unroll
    for (int h = 0; h < 32; ++h) wreg[h] = *(const v2f*)(Wb + h * HH);

    // ---- early independent loads for the softmax phase ----
    float mk = 0.f, bfin = 0.f; int im = 0;
    if (t < AA) {
        im   = indexmask[b * AA + t];
        mk   = maskp[b * AA + t];
        bfin = b_final[t % 3];             // t = 3*pair + k
    }
    if (t < 3 * HH) {
        int h = t / 3, k = t - 3 * h;
        wfT[k][h] = W_final[t];
    }

    // ---- graph offset: per-wave shuffle reduce ----
    #pragma unroll
    for (int o = 1; o < 64; o <<= 1) ov += __shfl_xor(ov, o, 64);
    const int off = ov;

    const int vv3 = v * v * 3;
    if (t < AA && t >= vv3) sc[t] = 0.f;   // zero pad tail (no reader before barrier 3)

    // ---- GEMV quarter (v==8 fast path removes predication + 9th row) ----
    const int hbase = hq * 32 + (lane & 31);
    const bool wrd  = (w < 4) && (lane < 32);
    float* dst = &pS[matB][hq][0][0];
    if (v == 8) gemv_phase<8, false>(nf, off, v, hbase, wrd, rdbuf, wreg, dst, c0);
    else        gemv_phase<MAXV, true>(nf, off, v, hbase, wrd, rdbuf, wreg, dst, c0);
    __syncthreads();                                   // barrier 1

    float a2lo = 0.f;                      // wave-7 readout partial (reg across barrier)
    if (w < 6) {
        // ---- combine 4 h-quarter partials; fold b_a2 into A (waves 0-5) ----
        #pragma unroll
        for (int rep = 0; rep < 3; ++rep) {
            int idx = t + rep * 384;       // 2 mats x 9 i x 64 float2-cols = 1152
            int m   = idx / 576;
            int rem = idx - m * 576;
            int i   = rem >> 6;
            int cc  = (rem & 63) << 1;
            float2 p0 = *(const float2*)&pS[m][0][i][cc];
            float2 p1 = *(const float2*)&pS[m][1][i][cc];
            float2 p2 = *(const float2*)&pS[m][2][i][cc];
            float2 p3 = *(const float2*)&pS[m][3][i][cc];
            float sx = (p0.x + p1.x) + (p2.x + p3.x);
            float sy = (p0.y + p1.y) + (p2.y + p3.y);
            if (m == 0) { sx += b_a2[cc]; sy += b_a2[cc + 1]; }
            *(float2*)&pS[m][0][i][cc] = make_float2(sx, sy);
        }
    } else if (w == 6) {
        // ---- readout hi-half partial (4 independent chains) ----
        float rd1 = rdbuf[64 + lane];
        float q0 = 0.f, q1 = 0.f, q2 = 0.f, q3 = 0.f;
        #pragma unroll
        for (int h = 0; h < 16; ++h) {
            q0 = fmaf(rl(rd1, h),      W_fcv1[(64 + h)  * 64 + lane], q0);
            q1 = fmaf(rl(rd1, h + 16), W_fcv1[(80 + h)  * 64 + lane], q1);
            q2 = fmaf(rl(rd1, h + 32), W_fcv1[(96 + h)  * 64 + lane], q2);
            q3 = fmaf(rl(rd1, h + 48), W_fcv1[(112 + h) * 64 + lane], q3);
        }
        rout[lane] = (q0 + q1) + (q2 + q3);
    } else {
        // ---- readout lo-half partial (stays in register) ----
        float rd0 = rdbuf[lane];
        float q0 = b_fcv1[lane], q1 = 0.f, q2 = 0.f, q3 = 0.f;
        #pragma unroll
        for (int h = 0; h < 16; ++h) {
            q0 = fmaf(rl(rd0, h),      W_fcv1[h        * 64 + lane], q0);
            q1 = fmaf(rl(rd0, h + 16), W_fcv1[(16 + h) * 64 + lane], q1);
            q2 = fmaf(rl(rd0, h + 32), W_fcv1[(32 + h) * 64 + lane], q2);
            q3 = fmaf(rl(rd0, h + 48), W_fcv1[(48 + h) * 64 + lane], q3);
        }
        a2lo = (q0 + q1) + (q2 + q3);
    }
    __syncthreads();                                   // barrier 2

    // ---- pair scoring (4 indep accumulators) ∥ readout finish (wave 7) ----
    if (t < vv3) {
        const int pair = t / 3, k = t - 3 * pair;
        const int i = pair / v, j = pair - i * v;
        const float* ar = &pS[0][0][i][0];
        const float* br = &pS[1][0][j][0];
        const float* wk = &wfT[k][0];
        float s0 = 0.f, s1 = 0.f, s2 = 0.f, s3 = 0.f;
        #pragma unroll 8
        for (int h = 0; h < HH; h += 4) {
            float4 a4 = *(const float4*)(ar + h);
            float4 b4 = *(const float4*)(br + h);
            float4 w4 = *(const float4*)(wk + h);
            s0 = fmaf(fmaxf(a4.x + b4.x, 0.f), w4.x, s0);
            s1 = fmaf(fmaxf(a4.y + b4.y, 0.f), w4.y, s1);
            s2 = fmaf(fmaxf(a4.z + b4.z, 0.f), w4.z, s2);
            s3 = fmaf(fmaxf(a4.w + b4.w, 0.f), w4.w, s3);
        }
        sc[t] = bfin + ((s0 + s1) + (s2 + s3));
    } else if (w == 7) {
        float a2 = a2lo + rout[lane];
        float x = fmaxf(a2, 0.f) * W_fcv2[lane];
        #pragma unroll
        for (int o = 1; o < 64; o <<= 1) x += __shfl_xor(x, o, 64);
        if (lane == 0) readout_out[b] = x + b_fcv2[0];
    }
    __syncthreads();                                   // barrier 3

    // ---- gather + online softmax: single cross-wave barrier ----
    float x = -FLT_MAX;
    if (t < AA) x = sc[im] + mk;
    float m_w = x;
    #pragma unroll
    for (int o = 1; o < 64; o <<= 1) m_w = fmaxf(m_w, __shfl_xor(m_w, o, 64));
    float e = (t < AA) ? __expf(x - m_w) : 0.f;
    float s_w = e;
    #pragma unroll
    for (int o = 1; o < 64; o <<= 1) s_w += __shfl_xor(s_w, o, 64);
    if (lane == 0 && w < 4) xr2[w] = make_float2(m_w, s_w);
    __syncthreads();                                   // barrier 4
    if (t < AA) {
        float2 p0 = xr2[0], p1 = xr2[1], p2 = xr2[2], p3 = xr2[3];
        float m = fmaxf(fmaxf(p0.x, p1.x), fmaxf(p2.x, p3.x));
        float denom = p0.y * __expf(p0.x - m) + p1.y * __expf(p1.x - m)
                    + p2.y * __expf(p2.x - m) + p3.y * __expf(p3.x - m);
        float f = __expf(m_w - m);
        probs_out[b * AA + t] = e * f * __builtin_amdgcn_rcpf(denom);
    }
}

extern "C" void kernel_launch(void* const* d_in, const int* in_sizes, int n_in,
                              void* d_out, int out_size, void* d_ws, size_t ws_size,
                              hipStream_t stream) {
    const float* nf      = (const float*)d_in[0];
    // d_in[1] = len_vec (==1 for in-graph pairs) -> unused
    const float* maskp   = (const float*)d_in[2];
    const float* W_fcv1  = (const float*)d_in[3];
    const float* b_fcv1  = (const float*)d_in[4];
    const float* W_fcv2  = (const float*)d_in[5];
    const float* b_fcv2  = (const float*)d_in[6];
    const float* W_a2    = (const float*)d_in[7];
    const float* b_a2    = (const float*)d_in[8];
    const float* W_final = (const float*)d_in[9];
    const float* b_final = (const float*)d_in[10];
    const int*   indexmask = (const int*)d_in[11];
    // d_in[12] = segment_ids (contiguous blocks) -> offsets derived from bnn
    const int*   bnn       = (const int*)d_in[13];

    float* probs   = (float*)d_out;
    float* readout = probs + BB * AA;

    apm_fused<<<BB, 512, 0, stream>>>(nf, maskp, W_fcv1, b_fcv1, W_fcv2, b_fcv2,
                                      W_a2, b_a2, W_final, b_final,
                                      indexmask, bnn, probs, readout);
}